// Round 1
// baseline (3507.809 us; speedup 1.0000x reference)
//
#include <hip/hip_runtime.h>
#include <math.h>

// ---------------- degree / norm ----------------
__global__ void deg_init_k(float* __restrict__ deg, int n) {
    int i = blockIdx.x * 256 + threadIdx.x;
    if (i < n) deg[i] = 1.0f;  // self-loop
}
__global__ void deg_acc_k(const int* __restrict__ dst, float* __restrict__ deg, int e) {
    int i = blockIdx.x * 256 + threadIdx.x;
    if (i < e) atomicAdd(&deg[dst[i]], 1.0f);
}
__global__ void deg_rsqrt_k(float* __restrict__ deg, int n) {
    int i = blockIdx.x * 256 + threadIdx.x;
    if (i < n) deg[i] = rsqrtf(deg[i]);
}

// ---------------- GEMM: C[n,COLS] = A[n,128] @ W[128,COLS] ----------------
// W staged in LDS; 4x4 register tile per thread; 256 threads/block.
template<int COLS>
__global__ __launch_bounds__(256) void gemm_k(const float* __restrict__ A,
                                              const float* __restrict__ W,
                                              float* __restrict__ C, int nrows) {
    constexpr int TC = COLS / 4;    // col groups (32 or 16)
    constexpr int TR = 256 / TC;    // row groups (8 or 16)
    constexpr int ROWS = TR * 4;    // rows per block (32 or 64)
    __shared__ float Ws[128 * COLS];
    int tid = threadIdx.x;
    for (int i = tid; i < 128 * COLS / 4; i += 256)
        ((float4*)Ws)[i] = ((const float4*)W)[i];
    __syncthreads();
    int tc = tid % TC, tr = tid / TC;
    int r0 = blockIdx.x * ROWS + tr * 4;
    float acc[4][4] = {};
    for (int k4 = 0; k4 < 128; k4 += 4) {
        float4 a[4];
#pragma unroll
        for (int i = 0; i < 4; ++i) {
            int r = r0 + i;
            a[i] = (r < nrows) ? *(const float4*)&A[(long)r * 128 + k4]
                               : make_float4(0.f, 0.f, 0.f, 0.f);
        }
#pragma unroll
        for (int kk = 0; kk < 4; ++kk) {
            float4 w = *(const float4*)&Ws[(k4 + kk) * COLS + tc * 4];
#pragma unroll
            for (int i = 0; i < 4; ++i) {
                float av = (&a[i].x)[kk];
                acc[i][0] = fmaf(av, w.x, acc[i][0]);
                acc[i][1] = fmaf(av, w.y, acc[i][1]);
                acc[i][2] = fmaf(av, w.z, acc[i][2]);
                acc[i][3] = fmaf(av, w.w, acc[i][3]);
            }
        }
    }
#pragma unroll
    for (int i = 0; i < 4; ++i) {
        int r = r0 + i;
        if (r < nrows) {
            float4 o = make_float4(acc[i][0], acc[i][1], acc[i][2], acc[i][3]);
            *(float4*)&C[(long)r * COLS + tc * 4] = o;
        }
    }
}

// ---------------- self-loop init: agg[n] = C[n] * dinv[n]^2 ----------------
template<int NCHUNK, int CS, int AS>
__global__ void init_self_k(const float* __restrict__ C, const float* __restrict__ dinv,
                            float* __restrict__ agg, int n) {
    int tid = blockIdx.x * 256 + threadIdx.x;
    if (tid >= n * NCHUNK) return;
    int nd = tid / NCHUNK, c = tid % NCHUNK;
    float w = dinv[nd] * dinv[nd];
    float4 v = *(const float4*)&C[(long)nd * CS + c * 4];
    float4 o = make_float4(v.x * w, v.y * w, v.z * w, v.w * w);
    *(float4*)&agg[(long)nd * AS + c * 4] = o;
}

// ---------------- edge scatter: agg[dst] += C[src]*dinv[src]*dinv[dst] ----------------
template<int NCHUNK, int CS, int AS>
__global__ void scatter_k(const int* __restrict__ src, const int* __restrict__ dst,
                          const float* __restrict__ dinv, const float* __restrict__ C,
                          float* __restrict__ agg, int e) {
    long tid = (long)blockIdx.x * 256 + threadIdx.x;
    if (tid >= (long)e * NCHUNK) return;
    int ei = (int)(tid / NCHUNK), c = (int)(tid % NCHUNK);
    int s = src[ei], d = dst[ei];
    float w = dinv[s] * dinv[d];
    float4 v = *(const float4*)&C[(long)s * CS + c * 4];
    float* ap = &agg[(long)d * AS + c * 4];
    atomicAdd(ap + 0, v.x * w);
    atomicAdd(ap + 1, v.y * w);
    atomicAdd(ap + 2, v.z * w);
    atomicAdd(ap + 3, v.w * w);
}

// ---------------- fused bias + LayerNorm + ReLU (one wave per row, H=128) ----------------
__global__ void ln_relu_k(const float* __restrict__ agg, const float* __restrict__ bias,
                          const float* __restrict__ g, const float* __restrict__ b,
                          float* __restrict__ out, int n) {
    int wid = (blockIdx.x * 256 + threadIdx.x) >> 6;
    int lane = threadIdx.x & 63;
    if (wid >= n) return;
    const float* row = agg + (long)wid * 128;
    float t0 = row[lane] + bias[lane];
    float t1 = row[lane + 64] + bias[lane + 64];
    float s = t0 + t1;
#pragma unroll
    for (int off = 32; off; off >>= 1) s += __shfl_xor(s, off);
    float mu = s * (1.f / 128.f);
    float d0 = t0 - mu, d1 = t1 - mu;
    float v = d0 * d0 + d1 * d1;
#pragma unroll
    for (int off = 32; off; off >>= 1) v += __shfl_xor(v, off);
    float rstd = rsqrtf(v * (1.f / 128.f) + 1e-5f);
    float y0 = fmaxf(0.f, d0 * rstd * g[lane] + b[lane]);
    float y1 = fmaxf(0.f, d1 * rstd * g[lane + 64] + b[lane + 64]);
    out[(long)wid * 128 + lane] = y0;
    out[(long)wid * 128 + lane + 64] = y1;
}

// ---------------- fused bias + log_softmax (one wave per row, OUT=40) ----------------
__global__ void lsm_k(const float* __restrict__ agg, const float* __restrict__ b2,
                      float* __restrict__ out, int n) {
    int wid = (blockIdx.x * 256 + threadIdx.x) >> 6;
    int lane = threadIdx.x & 63;
    if (wid >= n) return;
    float v = (lane < 40) ? agg[(long)wid * 40 + lane] + b2[lane] : -INFINITY;
    float m = v;
#pragma unroll
    for (int off = 32; off; off >>= 1) m = fmaxf(m, __shfl_xor(m, off));
    float e = (lane < 40) ? expf(v - m) : 0.f;
    float s = e;
#pragma unroll
    for (int off = 32; off; off >>= 1) s += __shfl_xor(s, off);
    float r = v - m - logf(s);
    if (lane < 40) out[(long)wid * 40 + lane] = r;
}

// ---------------- pad W2 [128,40] -> Wp [128,64] (zeros) ----------------
__global__ void pad_w2_k(const float* __restrict__ W2, float* __restrict__ Wp) {
    int i = blockIdx.x * 256 + threadIdx.x;
    if (i >= 128 * 64) return;
    int k = i >> 6, j = i & 63;
    Wp[i] = (j < 40) ? W2[k * 40 + j] : 0.f;
}

extern "C" void kernel_launch(void* const* d_in, const int* in_sizes, int n_in,
                              void* d_out, int out_size, void* d_ws, size_t ws_size,
                              hipStream_t stream) {
    const float* x    = (const float*)d_in[0];
    const float* W0   = (const float*)d_in[1];
    const float* b0   = (const float*)d_in[2];
    const float* W1   = (const float*)d_in[3];
    const float* b1   = (const float*)d_in[4];
    const float* W2   = (const float*)d_in[5];
    const float* b2   = (const float*)d_in[6];
    const float* ln1g = (const float*)d_in[7];
    const float* ln1b = (const float*)d_in[8];
    const float* ln2g = (const float*)d_in[9];
    const float* ln2b = (const float*)d_in[10];
    const int*   ei   = (const int*)d_in[11];

    const int N = in_sizes[0] / 128;   // 50000
    const int E = in_sizes[11] / 2;    // 800000
    const int* esrc = ei;
    const int* edst = ei + E;
    float* out = (float*)d_out;

    float* wsf  = (float*)d_ws;
    float* dinv = wsf;                      // N
    float* bufA = wsf + N;                  // N*128 (GEMM out; N*64 for layer 3)
    float* bufB = bufA + (long)N * 128;     // N*128 (agg / h; N*40 for layer 3)
    float* Wp   = bufB + (long)N * 128;     // 128*64

    dim3 blk(256);
    // degree + norm
    deg_init_k<<<(N + 255) / 256, blk, 0, stream>>>(dinv, N);
    deg_acc_k<<<(E + 255) / 256, blk, 0, stream>>>(edst, dinv, E);
    deg_rsqrt_k<<<(N + 255) / 256, blk, 0, stream>>>(dinv, N);

    // ---- layer 1 ----
    gemm_k<128><<<(N + 31) / 32, blk, 0, stream>>>(x, W0, bufA, N);
    init_self_k<32, 128, 128><<<((long)N * 32 + 255) / 256, blk, 0, stream>>>(bufA, dinv, bufB, N);
    scatter_k<32, 128, 128><<<((long)E * 32 + 255) / 256, blk, 0, stream>>>(esrc, edst, dinv, bufA, bufB, E);
    ln_relu_k<<<(N + 3) / 4, blk, 0, stream>>>(bufB, b0, ln1g, ln1b, bufB, N);

    // ---- layer 2 ----
    gemm_k<128><<<(N + 31) / 32, blk, 0, stream>>>(bufB, W1, bufA, N);
    init_self_k<32, 128, 128><<<((long)N * 32 + 255) / 256, blk, 0, stream>>>(bufA, dinv, bufB, N);
    scatter_k<32, 128, 128><<<((long)E * 32 + 255) / 256, blk, 0, stream>>>(esrc, edst, dinv, bufA, bufB, E);
    ln_relu_k<<<(N + 3) / 4, blk, 0, stream>>>(bufB, b1, ln2g, ln2b, bufB, N);

    // ---- layer 3 ----
    pad_w2_k<<<(128 * 64 + 255) / 256, blk, 0, stream>>>(W2, Wp);
    gemm_k<64><<<(N + 63) / 64, blk, 0, stream>>>(bufB, Wp, bufA, N);
    init_self_k<10, 64, 40><<<((long)N * 10 + 255) / 256, blk, 0, stream>>>(bufA, dinv, bufB, N);
    scatter_k<10, 64, 40><<<((long)E * 10 + 255) / 256, blk, 0, stream>>>(esrc, edst, dinv, bufA, bufB, E);
    lsm_k<<<(N + 3) / 4, blk, 0, stream>>>(bufB, b2, out, N);
}

// Round 2
// 592.879 us; speedup vs baseline: 5.9166x; 5.9166x over previous
//
#include <hip/hip_runtime.h>
#include <math.h>

// ---------------- CSR build ----------------
__global__ void zero_int_k(int* __restrict__ p, int n) {
    int i = blockIdx.x * 256 + threadIdx.x;
    if (i < n) p[i] = 0;
}
__global__ void count_k(const int* __restrict__ dst, int* __restrict__ counts, int e) {
    int i = blockIdx.x * 256 + threadIdx.x;
    if (i < e) atomicAdd(&counts[dst[i]], 1);
}
// dinv[i] = rsqrt(counts[i] + 1)   (+1 = self loop)
__global__ void dinv_k(const int* __restrict__ counts, float* __restrict__ dinv, int n) {
    int i = blockIdx.x * 256 + threadIdx.x;
    if (i < n) dinv[i] = rsqrtf((float)counts[i] + 1.0f);
}
// single-block exclusive scan: offs[0]=0, offs[i+1]=sum(counts[0..i])
__global__ __launch_bounds__(1024) void scan_k(const int* __restrict__ counts,
                                               int* __restrict__ offs, int n) {
    __shared__ int sd[1024];
    __shared__ int carry_s;
    int tid = threadIdx.x;
    if (tid == 0) { carry_s = 0; offs[0] = 0; }
    __syncthreads();
    for (int base = 0; base < n; base += 1024) {
        int i = base + tid;
        int v = (i < n) ? counts[i] : 0;
        sd[tid] = v;
        __syncthreads();
        for (int off = 1; off < 1024; off <<= 1) {
            int t = (tid >= off) ? sd[tid - off] : 0;
            __syncthreads();
            sd[tid] += t;
            __syncthreads();
        }
        int incl = sd[tid];
        int carry = carry_s;
        if (i < n) offs[i + 1] = carry + incl;
        __syncthreads();
        if (tid == 1023) carry_s = carry + sd[1023];
        __syncthreads();
    }
}
__global__ void copy_int_k(const int* __restrict__ a, int* __restrict__ b, int n) {
    int i = blockIdx.x * 256 + threadIdx.x;
    if (i < n) b[i] = a[i];
}
__global__ void fill_csr_k(const int* __restrict__ src, const int* __restrict__ dst,
                           int* __restrict__ cursor, int* __restrict__ csr, int e) {
    int i = blockIdx.x * 256 + threadIdx.x;
    if (i < e) {
        int p = atomicAdd(&cursor[dst[i]], 1);
        csr[p] = src[i];
    }
}

// ---------------- GEMM: Cs[n,COLS] = (A[n,128] @ W[128,COLS]) * dinv[row] ----------------
template<int COLS>
__global__ __launch_bounds__(256) void gemm_k(const float* __restrict__ A,
                                              const float* __restrict__ W,
                                              const float* __restrict__ dinv,
                                              float* __restrict__ C, int nrows) {
    constexpr int TC = COLS / 4;
    constexpr int TR = 256 / TC;
    constexpr int ROWS = TR * 4;
    __shared__ float Ws[128 * COLS];
    int tid = threadIdx.x;
    for (int i = tid; i < 128 * COLS / 4; i += 256)
        ((float4*)Ws)[i] = ((const float4*)W)[i];
    __syncthreads();
    int tc = tid % TC, tr = tid / TC;
    int r0 = blockIdx.x * ROWS + tr * 4;
    float acc[4][4] = {};
    for (int k4 = 0; k4 < 128; k4 += 4) {
        float4 a[4];
#pragma unroll
        for (int i = 0; i < 4; ++i) {
            int r = r0 + i;
            a[i] = (r < nrows) ? *(const float4*)&A[(long)r * 128 + k4]
                               : make_float4(0.f, 0.f, 0.f, 0.f);
        }
#pragma unroll
        for (int kk = 0; kk < 4; ++kk) {
            float4 w = *(const float4*)&Ws[(k4 + kk) * COLS + tc * 4];
#pragma unroll
            for (int i = 0; i < 4; ++i) {
                float av = (&a[i].x)[kk];
                acc[i][0] = fmaf(av, w.x, acc[i][0]);
                acc[i][1] = fmaf(av, w.y, acc[i][1]);
                acc[i][2] = fmaf(av, w.z, acc[i][2]);
                acc[i][3] = fmaf(av, w.w, acc[i][3]);
            }
        }
    }
#pragma unroll
    for (int i = 0; i < 4; ++i) {
        int r = r0 + i;
        if (r < nrows) {
            float s = dinv[r];
            float4 o = make_float4(acc[i][0] * s, acc[i][1] * s, acc[i][2] * s, acc[i][3] * s);
            *(float4*)&C[(long)r * COLS + tc * 4] = o;
        }
    }
}

// ---------------- fused CSR-gather aggregate + bias + LayerNorm + ReLU ----------------
// one wave per node; Cs is dinv[row]-prescaled; agg = dinv[d]*(Cs[d] + sum Cs[src])
__global__ __launch_bounds__(256) void agg_ln_relu_k(const float* __restrict__ Cs,
                                                     const int* __restrict__ offs,
                                                     const int* __restrict__ csr,
                                                     const float* __restrict__ dinv,
                                                     const float* __restrict__ bias,
                                                     const float* __restrict__ g,
                                                     const float* __restrict__ b,
                                                     float* __restrict__ out, int n) {
    int wid = (blockIdx.x * 256 + threadIdx.x) >> 6;
    int lane = threadIdx.x & 63;
    if (wid >= n) return;
    float a0 = Cs[(long)wid * 128 + lane];       // self term
    float a1 = Cs[(long)wid * 128 + 64 + lane];
    int beg = offs[wid], end = offs[wid + 1];
    for (int j = beg; j < end; j += 64) {
        int myidx = (j + lane < end) ? csr[j + lane] : 0;
        int cnt = min(64, end - j);
        for (int k = 0; k < cnt; ++k) {
            long s = (long)__shfl(myidx, k);
            a0 += Cs[s * 128 + lane];
            a1 += Cs[s * 128 + 64 + lane];
        }
    }
    float w = dinv[wid];
    float t0 = a0 * w + bias[lane];
    float t1 = a1 * w + bias[lane + 64];
    float s = t0 + t1;
#pragma unroll
    for (int off = 32; off; off >>= 1) s += __shfl_xor(s, off);
    float mu = s * (1.f / 128.f);
    float d0 = t0 - mu, d1 = t1 - mu;
    float v = d0 * d0 + d1 * d1;
#pragma unroll
    for (int off = 32; off; off >>= 1) v += __shfl_xor(v, off);
    float rstd = rsqrtf(v * (1.f / 128.f) + 1e-5f);
    float y0 = fmaxf(0.f, d0 * rstd * g[lane] + b[lane]);
    float y1 = fmaxf(0.f, d1 * rstd * g[lane + 64] + b[lane + 64]);
    out[(long)wid * 128 + lane] = y0;
    out[(long)wid * 128 + lane + 64] = y1;
}

// ---------------- fused CSR-gather aggregate + bias + log_softmax (64-col padded Cs) ----------------
__global__ __launch_bounds__(256) void agg_lsm_k(const float* __restrict__ Cs,
                                                 const int* __restrict__ offs,
                                                 const int* __restrict__ csr,
                                                 const float* __restrict__ dinv,
                                                 const float* __restrict__ b2,
                                                 float* __restrict__ out, int n) {
    int wid = (blockIdx.x * 256 + threadIdx.x) >> 6;
    int lane = threadIdx.x & 63;
    if (wid >= n) return;
    float a = Cs[(long)wid * 64 + lane];
    int beg = offs[wid], end = offs[wid + 1];
    for (int j = beg; j < end; j += 64) {
        int myidx = (j + lane < end) ? csr[j + lane] : 0;
        int cnt = min(64, end - j);
        for (int k = 0; k < cnt; ++k) {
            long s = (long)__shfl(myidx, k);
            a += Cs[s * 64 + lane];
        }
    }
    float v = (lane < 40) ? a * dinv[wid] + b2[lane] : -INFINITY;
    float m = v;
#pragma unroll
    for (int off = 32; off; off >>= 1) m = fmaxf(m, __shfl_xor(m, off));
    float e = (lane < 40) ? expf(v - m) : 0.f;
    float s = e;
#pragma unroll
    for (int off = 32; off; off >>= 1) s += __shfl_xor(s, off);
    float r = v - m - logf(s);
    if (lane < 40) out[(long)wid * 40 + lane] = r;
}

// ---------------- pad W2 [128,40] -> Wp [128,64] ----------------
__global__ void pad_w2_k(const float* __restrict__ W2, float* __restrict__ Wp) {
    int i = blockIdx.x * 256 + threadIdx.x;
    if (i >= 128 * 64) return;
    int k = i >> 6, j = i & 63;
    Wp[i] = (j < 40) ? W2[k * 40 + j] : 0.f;
}

extern "C" void kernel_launch(void* const* d_in, const int* in_sizes, int n_in,
                              void* d_out, int out_size, void* d_ws, size_t ws_size,
                              hipStream_t stream) {
    const float* x    = (const float*)d_in[0];
    const float* W0   = (const float*)d_in[1];
    const float* b0   = (const float*)d_in[2];
    const float* W1   = (const float*)d_in[3];
    const float* b1   = (const float*)d_in[4];
    const float* W2   = (const float*)d_in[5];
    const float* b2   = (const float*)d_in[6];
    const float* ln1g = (const float*)d_in[7];
    const float* ln1b = (const float*)d_in[8];
    const float* ln2g = (const float*)d_in[9];
    const float* ln2b = (const float*)d_in[10];
    const int*   ei   = (const int*)d_in[11];

    const int N = in_sizes[0] / 128;   // 50000
    const int E = in_sizes[11] / 2;    // 800000
    const int* esrc = ei;
    const int* edst = ei + E;
    float* out = (float*)d_out;

    const int Npad = ((N + 255) / 256) * 256;

    int* counts = (int*)d_ws;               // Npad
    int* offs   = counts + Npad;            // Npad (uses N+1)
    int* cursor = offs + Npad;              // Npad
    int* csr    = cursor + Npad;            // E (800000, multiple of 4)
    float* dinv = (float*)(csr + E);        // Npad
    float* bufA = dinv + Npad;              // N*128
    float* bufB = bufA + (long)N * 128;     // N*128
    float* Wp   = bufB + (long)N * 128;     // 128*64

    dim3 blk(256);
    int gN = (N + 255) / 256, gE = (E + 255) / 256;

    // ---- CSR build + norm ----
    zero_int_k<<<gN, blk, 0, stream>>>(counts, N);
    count_k<<<gE, blk, 0, stream>>>(edst, counts, E);
    dinv_k<<<gN, blk, 0, stream>>>(counts, dinv, N);
    scan_k<<<1, 1024, 0, stream>>>(counts, offs, N);
    copy_int_k<<<gN, blk, 0, stream>>>(offs, cursor, N);
    fill_csr_k<<<gE, blk, 0, stream>>>(esrc, edst, cursor, csr, E);

    // ---- layer 1 ----
    gemm_k<128><<<(N + 31) / 32, blk, 0, stream>>>(x, W0, dinv, bufA, N);
    agg_ln_relu_k<<<(N + 3) / 4, blk, 0, stream>>>(bufA, offs, csr, dinv, b0, ln1g, ln1b, bufB, N);

    // ---- layer 2 ----
    gemm_k<128><<<(N + 31) / 32, blk, 0, stream>>>(bufB, W1, dinv, bufA, N);
    agg_ln_relu_k<<<(N + 3) / 4, blk, 0, stream>>>(bufA, offs, csr, dinv, b1, ln2g, ln2b, bufB, N);

    // ---- layer 3 ----
    pad_w2_k<<<(128 * 64 + 255) / 256, blk, 0, stream>>>(W2, Wp);
    gemm_k<64><<<(N + 63) / 64, blk, 0, stream>>>(bufB, Wp, dinv, bufA, N);
    agg_lsm_k<<<(N + 3) / 4, blk, 0, stream>>>(bufA, offs, csr, dinv, b2, out, N);
}

// Round 3
// 305.070 us; speedup vs baseline: 11.4984x; 1.9434x over previous
//
#include <hip/hip_runtime.h>
#include <math.h>

typedef __attribute__((ext_vector_type(8))) short bf16x8;
typedef __attribute__((ext_vector_type(4))) float f32x4;

static __device__ __forceinline__ unsigned short f2bf(float f) {
    unsigned u = __float_as_uint(f);
    unsigned r = (u + 0x7fff + ((u >> 16) & 1)) >> 16;  // RNE
    return (unsigned short)r;
}
static __device__ __forceinline__ float bf2f(unsigned short h) {
    return __uint_as_float(((unsigned)h) << 16);
}

// ---------------- CSR build ----------------
__global__ void zero_int_k(int* __restrict__ p, int n) {
    int i = blockIdx.x * 256 + threadIdx.x;
    if (i < n) p[i] = 0;
}
__global__ void count_k(const int* __restrict__ dst, int* __restrict__ counts, int e) {
    int i = blockIdx.x * 256 + threadIdx.x;
    if (i < e) atomicAdd(&counts[dst[i]], 1);
}
__global__ void dinv_k(const int* __restrict__ counts, float* __restrict__ dinv, int n) {
    int i = blockIdx.x * 256 + threadIdx.x;
    if (i < n) dinv[i] = rsqrtf((float)counts[i] + 1.0f);
}
// hierarchical scan: offs[i+1] = inclusive scan of counts (block-local), bsum[b] = block total
__global__ __launch_bounds__(1024) void scan1_k(const int* __restrict__ counts,
                                                int* __restrict__ offs,
                                                int* __restrict__ bsum, int n) {
    __shared__ int ws[16];
    int tid = threadIdx.x;
    int i = blockIdx.x * 1024 + tid;
    int lane = tid & 63, w = tid >> 6;
    int s = (i < n) ? counts[i] : 0;
#pragma unroll
    for (int o = 1; o < 64; o <<= 1) { int t = __shfl_up(s, o); if (lane >= o) s += t; }
    if (lane == 63) ws[w] = s;
    __syncthreads();
    if (w == 0) {
        int x = (lane < 16) ? ws[lane] : 0;
#pragma unroll
        for (int o = 1; o < 16; o <<= 1) { int t = __shfl_up(x, o); if (lane >= o) x += t; }
        if (lane < 16) ws[lane] = x;
    }
    __syncthreads();
    int base = (w > 0) ? ws[w - 1] : 0;
    int incl = base + s;
    if (i < n) offs[i + 1] = incl;
    if (tid == 1023) bsum[blockIdx.x] = incl;
}
__global__ void scan2_k(int* __restrict__ bsum, int nb) {  // 1 block, 64 threads; nb<=64
    int lane = threadIdx.x;
    int v = (lane < nb) ? bsum[lane] : 0;
#pragma unroll
    for (int o = 1; o < 64; o <<= 1) { int t = __shfl_up(v, o); if (lane >= o) v += t; }
    if (lane < nb) bsum[lane] = v;
}
__global__ void scan3_k(int* __restrict__ offs, const int* __restrict__ bsum,
                        int* __restrict__ cursor, int n) {
    int i = blockIdx.x * 256 + threadIdx.x;
    if (i == 0) offs[0] = 0;
    if (i < n) {
        int b = i >> 10;
        int v = offs[i + 1] + ((b > 0) ? bsum[b - 1] : 0);
        offs[i + 1] = v;
    }
}
__global__ void copy_int_k(const int* __restrict__ a, int* __restrict__ b, int n) {
    int i = blockIdx.x * 256 + threadIdx.x;
    if (i < n) b[i] = a[i];
}
__global__ void fill_csr_k(const int* __restrict__ src, const int* __restrict__ dst,
                           int* __restrict__ cursor, int* __restrict__ csr, int e) {
    int i = blockIdx.x * 256 + threadIdx.x;
    if (i < e) {
        int p = atomicAdd(&cursor[dst[i]], 1);
        csr[p] = src[i];
    }
}

// ---------------- W prepack: fp32 [128,cin] -> fragment-ordered bf16 hi/lo, zero-pad to COLS ----------------
// frag layout for mfma_f32_16x16x32_bf16 B-operand: lane=(col%16)+((k>>3)&3)*16, j=k&7, ks=k/32
template<int COLS>
__global__ void pack_w_k(const float* __restrict__ W, int cin,
                         unsigned short* __restrict__ hi, unsigned short* __restrict__ lo) {
    int i = blockIdx.x * 256 + threadIdx.x;
    if (i >= 128 * COLS) return;
    int k = i / COLS, col = i % COLS;
    float v = (col < cin) ? W[k * cin + col] : 0.f;
    unsigned short h = f2bf(v);
    unsigned short l = f2bf(v - bf2f(h));
    int ct = col >> 4, ks = k >> 5, ln = (col & 15) + (((k >> 3) & 3) << 4), j = k & 7;
    int pos = (((ct * 4 + ks) * 64 + ln) << 3) + j;
    hi[pos] = h; lo[pos] = l;
}

// ---------------- MFMA GEMM: Cs[n,COLS] = (A[n,128] @ W) * dinv[row] ----------------
// split-bf16: A = Ahi + Alo; C ~= Ahi*Bhi + Alo*Bhi + Ahi*Blo. 4 waves/block, 16 rows/wave, no LDS.
template<int COLS>
__global__ __launch_bounds__(256) void mfma_gemm_k(const float* __restrict__ A,
                                                   const unsigned short* __restrict__ Whi,
                                                   const unsigned short* __restrict__ Wlo,
                                                   const float* __restrict__ dinv,
                                                   float* __restrict__ C, int nrows) {
    int wave = threadIdx.x >> 6, lane = threadIdx.x & 63;
    int r0 = blockIdx.x * 64 + wave * 16;
    int arow = min(r0 + (lane & 15), nrows - 1);
    int kbase = (lane >> 4) * 8;

    bf16x8 ahi[4], alo[4];
#pragma unroll
    for (int ks = 0; ks < 4; ++ks) {
        const float* ap = &A[(long)arow * 128 + ks * 32 + kbase];
        float4 f0 = *(const float4*)ap;
        float4 f1 = *(const float4*)(ap + 4);
        float fv[8] = {f0.x, f0.y, f0.z, f0.w, f1.x, f1.y, f1.z, f1.w};
#pragma unroll
        for (int j = 0; j < 8; ++j) {
            unsigned short h = f2bf(fv[j]);
            ahi[ks][j] = (short)h;
            alo[ks][j] = (short)f2bf(fv[j] - bf2f(h));
        }
    }
    float dscale[4];
#pragma unroll
    for (int r = 0; r < 4; ++r) {
        int orow = r0 + (lane >> 4) * 4 + r;
        dscale[r] = (orow < nrows) ? dinv[orow] : 0.f;
    }
#pragma unroll
    for (int ct = 0; ct < COLS / 16; ct += 2) {
        f32x4 acc0 = {0.f, 0.f, 0.f, 0.f}, acc1 = {0.f, 0.f, 0.f, 0.f};
#pragma unroll
        for (int ks = 0; ks < 4; ++ks) {
            int fo0 = ((ct * 4 + ks) * 64 + lane) * 8;
            int fo1 = (((ct + 1) * 4 + ks) * 64 + lane) * 8;
            bf16x8 bhi0 = *(const bf16x8*)&Whi[fo0];
            bf16x8 blo0 = *(const bf16x8*)&Wlo[fo0];
            bf16x8 bhi1 = *(const bf16x8*)&Whi[fo1];
            bf16x8 blo1 = *(const bf16x8*)&Wlo[fo1];
            acc0 = __builtin_amdgcn_mfma_f32_16x16x32_bf16(ahi[ks], bhi0, acc0, 0, 0, 0);
            acc1 = __builtin_amdgcn_mfma_f32_16x16x32_bf16(ahi[ks], bhi1, acc1, 0, 0, 0);
            acc0 = __builtin_amdgcn_mfma_f32_16x16x32_bf16(alo[ks], bhi0, acc0, 0, 0, 0);
            acc1 = __builtin_amdgcn_mfma_f32_16x16x32_bf16(alo[ks], bhi1, acc1, 0, 0, 0);
            acc0 = __builtin_amdgcn_mfma_f32_16x16x32_bf16(ahi[ks], blo0, acc0, 0, 0, 0);
            acc1 = __builtin_amdgcn_mfma_f32_16x16x32_bf16(ahi[ks], blo1, acc1, 0, 0, 0);
        }
#pragma unroll
        for (int r = 0; r < 4; ++r) {
            int orow = r0 + (lane >> 4) * 4 + r;
            if (orow < nrows) {
                C[(long)orow * COLS + ct * 16 + (lane & 15)] = acc0[r] * dscale[r];
                C[(long)orow * COLS + (ct + 1) * 16 + (lane & 15)] = acc1[r] * dscale[r];
            }
        }
    }
}

// ---------------- fused CSR-gather aggregate + bias + LayerNorm + ReLU ----------------
// one wave/node; lane holds feats (2l, 2l+1); 4-edge unroll, dual accumulators
__global__ __launch_bounds__(256) void agg_ln_relu_k(const float* __restrict__ Cs,
                                                     const int* __restrict__ offs,
                                                     const int* __restrict__ csr,
                                                     const float* __restrict__ dinv,
                                                     const float* __restrict__ bias,
                                                     const float* __restrict__ g,
                                                     const float* __restrict__ b,
                                                     float* __restrict__ out, int n) {
    int wid = (blockIdx.x * 256 + threadIdx.x) >> 6;
    int lane = threadIdx.x & 63;
    if (wid >= n) return;
    const float2* C2 = (const float2*)Cs;
    float2 st = C2[(long)wid * 64 + lane];  // self term
    float ax = st.x, ay = st.y, bx = 0.f, by = 0.f;
    int beg = offs[wid], end = offs[wid + 1];
    int j = beg;
    while (j < end) {
        int take = min(64, end - j);
        int myidx = (lane < take) ? csr[j + lane] : 0;
        int k = 0;
        for (; k + 4 <= take; k += 4) {
            int i0 = __shfl(myidx, k), i1 = __shfl(myidx, k + 1);
            int i2 = __shfl(myidx, k + 2), i3 = __shfl(myidx, k + 3);
            float2 v0 = C2[(long)i0 * 64 + lane];
            float2 v1 = C2[(long)i1 * 64 + lane];
            float2 v2 = C2[(long)i2 * 64 + lane];
            float2 v3 = C2[(long)i3 * 64 + lane];
            ax += v0.x + v1.x; ay += v0.y + v1.y;
            bx += v2.x + v3.x; by += v2.y + v3.y;
        }
        for (; k < take; ++k) {
            int i0 = __shfl(myidx, k);
            float2 v0 = C2[(long)i0 * 64 + lane];
            ax += v0.x; ay += v0.y;
        }
        j += take;
    }
    float w = dinv[wid];
    float2 bia = ((const float2*)bias)[lane];
    float t0 = (ax + bx) * w + bia.x;
    float t1 = (ay + by) * w + bia.y;
    float s = t0 + t1;
#pragma unroll
    for (int off = 32; off; off >>= 1) s += __shfl_xor(s, off);
    float mu = s * (1.f / 128.f);
    float d0 = t0 - mu, d1 = t1 - mu;
    float v = d0 * d0 + d1 * d1;
#pragma unroll
    for (int off = 32; off; off >>= 1) v += __shfl_xor(v, off);
    float rstd = rsqrtf(v * (1.f / 128.f) + 1e-5f);
    float2 gv = ((const float2*)g)[lane];
    float2 bv = ((const float2*)b)[lane];
    float y0 = fmaxf(0.f, d0 * rstd * gv.x + bv.x);
    float y1 = fmaxf(0.f, d1 * rstd * gv.y + bv.y);
    ((float2*)out)[(long)wid * 64 + lane] = make_float2(y0, y1);
}

// ---------------- fused CSR-gather aggregate + bias + log_softmax (64-col Cs) ----------------
__global__ __launch_bounds__(256) void agg_lsm_k(const float* __restrict__ Cs,
                                                 const int* __restrict__ offs,
                                                 const int* __restrict__ csr,
                                                 const float* __restrict__ dinv,
                                                 const float* __restrict__ b2,
                                                 float* __restrict__ out, int n) {
    int wid = (blockIdx.x * 256 + threadIdx.x) >> 6;
    int lane = threadIdx.x & 63;
    if (wid >= n) return;
    float aa = Cs[(long)wid * 64 + lane], ab = 0.f;
    int beg = offs[wid], end = offs[wid + 1];
    int j = beg;
    while (j < end) {
        int take = min(64, end - j);
        int myidx = (lane < take) ? csr[j + lane] : 0;
        int k = 0;
        for (; k + 4 <= take; k += 4) {
            int i0 = __shfl(myidx, k), i1 = __shfl(myidx, k + 1);
            int i2 = __shfl(myidx, k + 2), i3 = __shfl(myidx, k + 3);
            float v0 = Cs[(long)i0 * 64 + lane];
            float v1 = Cs[(long)i1 * 64 + lane];
            float v2 = Cs[(long)i2 * 64 + lane];
            float v3 = Cs[(long)i3 * 64 + lane];
            aa += v0 + v1; ab += v2 + v3;
        }
        for (; k < take; ++k) {
            int i0 = __shfl(myidx, k);
            aa += Cs[(long)i0 * 64 + lane];
        }
        j += take;
    }
    float v = (lane < 40) ? (aa + ab) * dinv[wid] + b2[lane] : -INFINITY;
    float m = v;
#pragma unroll
    for (int off = 32; off; off >>= 1) m = fmaxf(m, __shfl_xor(m, off));
    float e = (lane < 40) ? expf(v - m) : 0.f;
    float s = e;
#pragma unroll
    for (int off = 32; off; off >>= 1) s += __shfl_xor(s, off);
    float r = v - m - logf(s);
    if (lane < 40) out[(long)wid * 40 + lane] = r;
}

extern "C" void kernel_launch(void* const* d_in, const int* in_sizes, int n_in,
                              void* d_out, int out_size, void* d_ws, size_t ws_size,
                              hipStream_t stream) {
    const float* x    = (const float*)d_in[0];
    const float* W0   = (const float*)d_in[1];
    const float* b0   = (const float*)d_in[2];
    const float* W1   = (const float*)d_in[3];
    const float* b1   = (const float*)d_in[4];
    const float* W2   = (const float*)d_in[5];
    const float* b2   = (const float*)d_in[6];
    const float* ln1g = (const float*)d_in[7];
    const float* ln1b = (const float*)d_in[8];
    const float* ln2g = (const float*)d_in[9];
    const float* ln2b = (const float*)d_in[10];
    const int*   ei   = (const int*)d_in[11];

    const int N = in_sizes[0] / 128;   // 50000
    const int E = in_sizes[11] / 2;    // 800000
    const int* esrc = ei;
    const int* edst = ei + E;
    float* out = (float*)d_out;

    const int Npad = ((N + 255) / 256) * 256;

    int* counts = (int*)d_ws;                       // Npad
    int* offs   = counts + Npad;                    // Npad (N+1 used)
    int* cursor = offs + Npad;                      // Npad
    int* bsum   = cursor + Npad;                    // 64
    int* csr    = bsum + 64;                        // E
    float* dinv = (float*)(csr + E);                // Npad
    float* bufA = dinv + Npad;                      // N*128
    float* bufB = bufA + (long)N * 128;             // N*128
    unsigned short* w0hi = (unsigned short*)(bufB + (long)N * 128);
    unsigned short* w0lo = w0hi + 16384;
    unsigned short* w1hi = w0lo + 16384;
    unsigned short* w1lo = w1hi + 16384;
    unsigned short* w2hi = w1lo + 16384;
    unsigned short* w2lo = w2hi + 8192;

    dim3 blk(256);
    int gN = (N + 255) / 256, gE = (E + 255) / 256;
    int nb1024 = (N + 1023) / 1024;

    // ---- CSR build + norm ----
    zero_int_k<<<gN, blk, 0, stream>>>(counts, N);
    count_k<<<gE, blk, 0, stream>>>(edst, counts, E);
    dinv_k<<<gN, blk, 0, stream>>>(counts, dinv, N);
    scan1_k<<<nb1024, 1024, 0, stream>>>(counts, offs, bsum, N);
    scan2_k<<<1, 64, 0, stream>>>(bsum, nb1024);
    scan3_k<<<gN, blk, 0, stream>>>(offs, bsum, cursor, N);
    copy_int_k<<<gN, blk, 0, stream>>>(offs, cursor, N);
    fill_csr_k<<<gE, blk, 0, stream>>>(esrc, edst, cursor, csr, E);

    // ---- W prepack (bf16 hi/lo, fragment order) ----
    pack_w_k<128><<<(128 * 128 + 255) / 256, blk, 0, stream>>>(W0, 128, w0hi, w0lo);
    pack_w_k<128><<<(128 * 128 + 255) / 256, blk, 0, stream>>>(W1, 128, w1hi, w1lo);
    pack_w_k<64><<<(128 * 64 + 255) / 256, blk, 0, stream>>>(W2, 40, w2hi, w2lo);

    int gG = (N + 63) / 64;
    // ---- layer 1 ----
    mfma_gemm_k<128><<<gG, blk, 0, stream>>>(x, w0hi, w0lo, dinv, bufA, N);
    agg_ln_relu_k<<<(N + 3) / 4, blk, 0, stream>>>(bufA, offs, csr, dinv, b0, ln1g, ln1b, bufB, N);
    // ---- layer 2 ----
    mfma_gemm_k<128><<<gG, blk, 0, stream>>>(bufB, w1hi, w1lo, dinv, bufA, N);
    agg_ln_relu_k<<<(N + 3) / 4, blk, 0, stream>>>(bufA, offs, csr, dinv, b1, ln2g, ln2b, bufB, N);
    // ---- layer 3 ----
    mfma_gemm_k<64><<<gG, blk, 0, stream>>>(bufB, w2hi, w2lo, dinv, bufA, N);
    agg_lsm_k<<<(N + 3) / 4, blk, 0, stream>>>(bufA, offs, csr, dinv, b2, out, N);
}

// Round 4
// 265.229 us; speedup vs baseline: 13.2256x; 1.1502x over previous
//
#include <hip/hip_runtime.h>
#include <math.h>

typedef __attribute__((ext_vector_type(8))) short bf16x8;
typedef __attribute__((ext_vector_type(4))) float f32x4;
typedef unsigned short u16;

static __device__ __forceinline__ u16 f2bf(float f) {
    unsigned u = __float_as_uint(f);
    unsigned r = (u + 0x7fff + ((u >> 16) & 1)) >> 16;  // RNE
    return (u16)r;
}
static __device__ __forceinline__ float bf2f(u16 h) {
    return __uint_as_float(((unsigned)h) << 16);
}
// packed pair (b1<<16)|b0 -> floats
static __device__ __forceinline__ float pk_lo(unsigned u) { return __uint_as_float(u << 16); }
static __device__ __forceinline__ float pk_hi(unsigned u) { return __uint_as_float(u & 0xffff0000u); }

// ---------------- CSR build ----------------
__global__ void zero_int_k(int* __restrict__ p, int n) {
    int i = blockIdx.x * 256 + threadIdx.x;
    if (i < n) p[i] = 0;
}
__global__ void count_k(const int* __restrict__ dst, int* __restrict__ counts, int e) {
    int i = blockIdx.x * 256 + threadIdx.x;
    if (i < e) atomicAdd(&counts[dst[i]], 1);
}
__global__ void dinv_k(const int* __restrict__ counts, float* __restrict__ dinv, int n) {
    int i = blockIdx.x * 256 + threadIdx.x;
    if (i < n) dinv[i] = rsqrtf((float)counts[i] + 1.0f);
}
__global__ __launch_bounds__(1024) void scan1_k(const int* __restrict__ counts,
                                                int* __restrict__ offs,
                                                int* __restrict__ bsum, int n) {
    __shared__ int ws[16];
    int tid = threadIdx.x;
    int i = blockIdx.x * 1024 + tid;
    int lane = tid & 63, w = tid >> 6;
    int s = (i < n) ? counts[i] : 0;
#pragma unroll
    for (int o = 1; o < 64; o <<= 1) { int t = __shfl_up(s, o); if (lane >= o) s += t; }
    if (lane == 63) ws[w] = s;
    __syncthreads();
    if (w == 0) {
        int x = (lane < 16) ? ws[lane] : 0;
#pragma unroll
        for (int o = 1; o < 16; o <<= 1) { int t = __shfl_up(x, o); if (lane >= o) x += t; }
        if (lane < 16) ws[lane] = x;
    }
    __syncthreads();
    int base = (w > 0) ? ws[w - 1] : 0;
    int incl = base + s;
    if (i < n) offs[i + 1] = incl;
    if (tid == 1023) bsum[blockIdx.x] = incl;
}
__global__ void scan2_k(int* __restrict__ bsum, int nb) {
    int lane = threadIdx.x;
    int v = (lane < nb) ? bsum[lane] : 0;
#pragma unroll
    for (int o = 1; o < 64; o <<= 1) { int t = __shfl_up(v, o); if (lane >= o) v += t; }
    if (lane < nb) bsum[lane] = v;
}
__global__ void scan3_k(int* __restrict__ offs, const int* __restrict__ bsum, int n) {
    int i = blockIdx.x * 256 + threadIdx.x;
    if (i == 0) offs[0] = 0;
    if (i < n) {
        int b = i >> 10;
        offs[i + 1] += (b > 0) ? bsum[b - 1] : 0;
    }
}
__global__ void copy_int_k(const int* __restrict__ a, int* __restrict__ b, int n) {
    int i = blockIdx.x * 256 + threadIdx.x;
    if (i < n) b[i] = a[i];
}
__global__ void fill_csr_k(const int* __restrict__ src, const int* __restrict__ dst,
                           int* __restrict__ cursor, int* __restrict__ csr, int e) {
    int i = blockIdx.x * 256 + threadIdx.x;
    if (i < e) {
        int p = atomicAdd(&cursor[dst[i]], 1);
        csr[p] = src[i];
    }
}

// ---------------- W prepack: fp32 [128,cin] -> fragment-ordered bf16 hi/lo ----------------
template<int COLS>
__global__ void pack_w_k(const float* __restrict__ W, int cin,
                         u16* __restrict__ hi, u16* __restrict__ lo) {
    int i = blockIdx.x * 256 + threadIdx.x;
    if (i >= 128 * COLS) return;
    int k = i / COLS, col = i % COLS;
    float v = (col < cin) ? W[k * cin + col] : 0.f;
    u16 h = f2bf(v);
    u16 l = f2bf(v - bf2f(h));
    int ct = col >> 4, ks = k >> 5, ln = (col & 15) + (((k >> 3) & 3) << 4), j = k & 7;
    int pos = (((ct * 4 + ks) * 64 + ln) << 3) + j;
    hi[pos] = h; lo[pos] = l;
}

// ---------------- layer-1 GEMM: fp32 A, hi/lo split (3 MFMA), bf16 C ----------------
template<int COLS>
__global__ __launch_bounds__(256) void mfma_gemm_f32a_k(const float* __restrict__ A,
                                                        const u16* __restrict__ Whi,
                                                        const u16* __restrict__ Wlo,
                                                        const float* __restrict__ dinv,
                                                        u16* __restrict__ C, int nrows) {
    int wave = threadIdx.x >> 6, lane = threadIdx.x & 63;
    int r0 = blockIdx.x * 64 + wave * 16;
    int arow = min(r0 + (lane & 15), nrows - 1);
    int kbase = (lane >> 4) * 8;

    bf16x8 ahi[4], alo[4];
#pragma unroll
    for (int ks = 0; ks < 4; ++ks) {
        const float* ap = &A[(long)arow * 128 + ks * 32 + kbase];
        float4 f0 = *(const float4*)ap;
        float4 f1 = *(const float4*)(ap + 4);
        float fv[8] = {f0.x, f0.y, f0.z, f0.w, f1.x, f1.y, f1.z, f1.w};
#pragma unroll
        for (int j = 0; j < 8; ++j) {
            u16 h = f2bf(fv[j]);
            ahi[ks][j] = (short)h;
            alo[ks][j] = (short)f2bf(fv[j] - bf2f(h));
        }
    }
    float dscale[4];
#pragma unroll
    for (int r = 0; r < 4; ++r) {
        int orow = r0 + (lane >> 4) * 4 + r;
        dscale[r] = (orow < nrows) ? dinv[orow] : 0.f;
    }
#pragma unroll
    for (int ct = 0; ct < COLS / 16; ct += 2) {
        f32x4 acc0 = {0.f, 0.f, 0.f, 0.f}, acc1 = {0.f, 0.f, 0.f, 0.f};
#pragma unroll
        for (int ks = 0; ks < 4; ++ks) {
            int fo0 = ((ct * 4 + ks) * 64 + lane) * 8;
            int fo1 = (((ct + 1) * 4 + ks) * 64 + lane) * 8;
            bf16x8 bhi0 = *(const bf16x8*)&Whi[fo0];
            bf16x8 blo0 = *(const bf16x8*)&Wlo[fo0];
            bf16x8 bhi1 = *(const bf16x8*)&Whi[fo1];
            bf16x8 blo1 = *(const bf16x8*)&Wlo[fo1];
            acc0 = __builtin_amdgcn_mfma_f32_16x16x32_bf16(ahi[ks], bhi0, acc0, 0, 0, 0);
            acc1 = __builtin_amdgcn_mfma_f32_16x16x32_bf16(ahi[ks], bhi1, acc1, 0, 0, 0);
            acc0 = __builtin_amdgcn_mfma_f32_16x16x32_bf16(alo[ks], bhi0, acc0, 0, 0, 0);
            acc1 = __builtin_amdgcn_mfma_f32_16x16x32_bf16(alo[ks], bhi1, acc1, 0, 0, 0);
            acc0 = __builtin_amdgcn_mfma_f32_16x16x32_bf16(ahi[ks], blo0, acc0, 0, 0, 0);
            acc1 = __builtin_amdgcn_mfma_f32_16x16x32_bf16(ahi[ks], blo1, acc1, 0, 0, 0);
        }
#pragma unroll
        for (int r = 0; r < 4; ++r) {
            int orow = r0 + (lane >> 4) * 4 + r;
            if (orow < nrows) {
                C[(long)orow * COLS + ct * 16 + (lane & 15)] = f2bf(acc0[r] * dscale[r]);
                C[(long)orow * COLS + (ct + 1) * 16 + (lane & 15)] = f2bf(acc1[r] * dscale[r]);
            }
        }
    }
}

// ---------------- layers 2/3 GEMM: bf16 A (2 MFMA), bf16 C ----------------
template<int COLS>
__global__ __launch_bounds__(256) void mfma_gemm_bf16a_k(const u16* __restrict__ A,
                                                         const u16* __restrict__ Whi,
                                                         const u16* __restrict__ Wlo,
                                                         const float* __restrict__ dinv,
                                                         u16* __restrict__ C, int nrows) {
    int wave = threadIdx.x >> 6, lane = threadIdx.x & 63;
    int r0 = blockIdx.x * 64 + wave * 16;
    int arow = min(r0 + (lane & 15), nrows - 1);
    int kbase = (lane >> 4) * 8;

    bf16x8 a[4];
#pragma unroll
    for (int ks = 0; ks < 4; ++ks)
        a[ks] = *(const bf16x8*)&A[(long)arow * 128 + ks * 32 + kbase];

    float dscale[4];
#pragma unroll
    for (int r = 0; r < 4; ++r) {
        int orow = r0 + (lane >> 4) * 4 + r;
        dscale[r] = (orow < nrows) ? dinv[orow] : 0.f;
    }
#pragma unroll
    for (int ct = 0; ct < COLS / 16; ct += 2) {
        f32x4 acc0 = {0.f, 0.f, 0.f, 0.f}, acc1 = {0.f, 0.f, 0.f, 0.f};
#pragma unroll
        for (int ks = 0; ks < 4; ++ks) {
            int fo0 = ((ct * 4 + ks) * 64 + lane) * 8;
            int fo1 = (((ct + 1) * 4 + ks) * 64 + lane) * 8;
            bf16x8 bhi0 = *(const bf16x8*)&Whi[fo0];
            bf16x8 blo0 = *(const bf16x8*)&Wlo[fo0];
            bf16x8 bhi1 = *(const bf16x8*)&Whi[fo1];
            bf16x8 blo1 = *(const bf16x8*)&Wlo[fo1];
            acc0 = __builtin_amdgcn_mfma_f32_16x16x32_bf16(a[ks], bhi0, acc0, 0, 0, 0);
            acc1 = __builtin_amdgcn_mfma_f32_16x16x32_bf16(a[ks], bhi1, acc1, 0, 0, 0);
            acc0 = __builtin_amdgcn_mfma_f32_16x16x32_bf16(a[ks], blo0, acc0, 0, 0, 0);
            acc1 = __builtin_amdgcn_mfma_f32_16x16x32_bf16(a[ks], blo1, acc1, 0, 0, 0);
        }
#pragma unroll
        for (int r = 0; r < 4; ++r) {
            int orow = r0 + (lane >> 4) * 4 + r;
            if (orow < nrows) {
                C[(long)orow * COLS + ct * 16 + (lane & 15)] = f2bf(acc0[r] * dscale[r]);
                C[(long)orow * COLS + (ct + 1) * 16 + (lane & 15)] = f2bf(acc1[r] * dscale[r]);
            }
        }
    }
}

// ---------------- fused CSR-gather aggregate + bias + LayerNorm + ReLU (bf16 Cs/h) ----------------
__global__ __launch_bounds__(256) void agg_ln_relu_k(const u16* __restrict__ Cs,
                                                     const int* __restrict__ offs,
                                                     const int* __restrict__ csr,
                                                     const float* __restrict__ dinv,
                                                     const float* __restrict__ bias,
                                                     const float* __restrict__ g,
                                                     const float* __restrict__ b,
                                                     u16* __restrict__ out, int n) {
    int wid = (blockIdx.x * 256 + threadIdx.x) >> 6;
    int lane = threadIdx.x & 63;
    if (wid >= n) return;
    const unsigned* C2 = (const unsigned*)Cs;  // packed bf16 pair per lane
    unsigned su = C2[(long)wid * 64 + lane];
    float ax = pk_lo(su), ay = pk_hi(su), bx2 = 0.f, by2 = 0.f;
    int beg = offs[wid], end = offs[wid + 1];
    int j = beg;
    while (j < end) {
        int take = min(64, end - j);
        int myidx = (lane < take) ? csr[j + lane] : 0;
        int k = 0;
        for (; k + 8 <= take; k += 8) {
            int i0 = __shfl(myidx, k),     i1 = __shfl(myidx, k + 1);
            int i2 = __shfl(myidx, k + 2), i3 = __shfl(myidx, k + 3);
            int i4 = __shfl(myidx, k + 4), i5 = __shfl(myidx, k + 5);
            int i6 = __shfl(myidx, k + 6), i7 = __shfl(myidx, k + 7);
            unsigned u0 = C2[(long)i0 * 64 + lane], u1 = C2[(long)i1 * 64 + lane];
            unsigned u2 = C2[(long)i2 * 64 + lane], u3 = C2[(long)i3 * 64 + lane];
            unsigned u4 = C2[(long)i4 * 64 + lane], u5 = C2[(long)i5 * 64 + lane];
            unsigned u6 = C2[(long)i6 * 64 + lane], u7 = C2[(long)i7 * 64 + lane];
            ax += pk_lo(u0) + pk_lo(u1) + pk_lo(u2) + pk_lo(u3);
            ay += pk_hi(u0) + pk_hi(u1) + pk_hi(u2) + pk_hi(u3);
            bx2 += pk_lo(u4) + pk_lo(u5) + pk_lo(u6) + pk_lo(u7);
            by2 += pk_hi(u4) + pk_hi(u5) + pk_hi(u6) + pk_hi(u7);
        }
        for (; k < take; ++k) {
            int i0 = __shfl(myidx, k);
            unsigned u0 = C2[(long)i0 * 64 + lane];
            ax += pk_lo(u0); ay += pk_hi(u0);
        }
        j += take;
    }
    float w = dinv[wid];
    float2 bia = ((const float2*)bias)[lane];
    float t0 = (ax + bx2) * w + bia.x;
    float t1 = (ay + by2) * w + bia.y;
    float s = t0 + t1;
#pragma unroll
    for (int off = 32; off; off >>= 1) s += __shfl_xor(s, off);
    float mu = s * (1.f / 128.f);
    float d0 = t0 - mu, d1 = t1 - mu;
    float v = d0 * d0 + d1 * d1;
#pragma unroll
    for (int off = 32; off; off >>= 1) v += __shfl_xor(v, off);
    float rstd = rsqrtf(v * (1.f / 128.f) + 1e-5f);
    float2 gv = ((const float2*)g)[lane];
    float2 bv = ((const float2*)b)[lane];
    float y0 = fmaxf(0.f, d0 * rstd * gv.x + bv.x);
    float y1 = fmaxf(0.f, d1 * rstd * gv.y + bv.y);
    ((unsigned*)out)[(long)wid * 64 + lane] = ((unsigned)f2bf(y1) << 16) | f2bf(y0);
}

// ---------------- fused CSR-gather aggregate + bias + log_softmax (bf16 Cs, 64-col) ----------------
__global__ __launch_bounds__(256) void agg_lsm_k(const u16* __restrict__ Cs,
                                                 const int* __restrict__ offs,
                                                 const int* __restrict__ csr,
                                                 const float* __restrict__ dinv,
                                                 const float* __restrict__ b2,
                                                 float* __restrict__ out, int n) {
    int wid = (blockIdx.x * 256 + threadIdx.x) >> 6;
    int lane = threadIdx.x & 63;
    if (wid >= n) return;
    float aa = bf2f(Cs[(long)wid * 64 + lane]), ab = 0.f;
    int beg = offs[wid], end = offs[wid + 1];
    int j = beg;
    while (j < end) {
        int take = min(64, end - j);
        int myidx = (lane < take) ? csr[j + lane] : 0;
        int k = 0;
        for (; k + 8 <= take; k += 8) {
            int i0 = __shfl(myidx, k),     i1 = __shfl(myidx, k + 1);
            int i2 = __shfl(myidx, k + 2), i3 = __shfl(myidx, k + 3);
            int i4 = __shfl(myidx, k + 4), i5 = __shfl(myidx, k + 5);
            int i6 = __shfl(myidx, k + 6), i7 = __shfl(myidx, k + 7);
            float v0 = bf2f(Cs[(long)i0 * 64 + lane]), v1 = bf2f(Cs[(long)i1 * 64 + lane]);
            float v2 = bf2f(Cs[(long)i2 * 64 + lane]), v3 = bf2f(Cs[(long)i3 * 64 + lane]);
            float v4 = bf2f(Cs[(long)i4 * 64 + lane]), v5 = bf2f(Cs[(long)i5 * 64 + lane]);
            float v6 = bf2f(Cs[(long)i6 * 64 + lane]), v7 = bf2f(Cs[(long)i7 * 64 + lane]);
            aa += v0 + v1 + v2 + v3;
            ab += v4 + v5 + v6 + v7;
        }
        for (; k < take; ++k) {
            int i0 = __shfl(myidx, k);
            aa += bf2f(Cs[(long)i0 * 64 + lane]);
        }
        j += take;
    }
    float v = (lane < 40) ? (aa + ab) * dinv[wid] + b2[lane] : -INFINITY;
    float m = v;
#pragma unroll
    for (int off = 32; off; off >>= 1) m = fmaxf(m, __shfl_xor(m, off));
    float e = (lane < 40) ? expf(v - m) : 0.f;
    float s = e;
#pragma unroll
    for (int off = 32; off; off >>= 1) s += __shfl_xor(s, off);
    float r = v - m - logf(s);
    if (lane < 40) out[(long)wid * 40 + lane] = r;
}

extern "C" void kernel_launch(void* const* d_in, const int* in_sizes, int n_in,
                              void* d_out, int out_size, void* d_ws, size_t ws_size,
                              hipStream_t stream) {
    const float* x    = (const float*)d_in[0];
    const float* W0   = (const float*)d_in[1];
    const float* b0   = (const float*)d_in[2];
    const float* W1   = (const float*)d_in[3];
    const float* b1   = (const float*)d_in[4];
    const float* W2   = (const float*)d_in[5];
    const float* b2   = (const float*)d_in[6];
    const float* ln1g = (const float*)d_in[7];
    const float* ln1b = (const float*)d_in[8];
    const float* ln2g = (const float*)d_in[9];
    const float* ln2b = (const float*)d_in[10];
    const int*   ei   = (const int*)d_in[11];

    const int N = in_sizes[0] / 128;   // 50000
    const int E = in_sizes[11] / 2;    // 800000
    const int* esrc = ei;
    const int* edst = ei + E;
    float* out = (float*)d_out;

    const int Npad = ((N + 255) / 256) * 256;

    int* counts = (int*)d_ws;                       // Npad
    int* offs   = counts + Npad;                    // Npad (N+1 used)
    int* cursor = offs + Npad;                      // Npad
    int* bsum   = cursor + Npad;                    // 64
    int* csr    = bsum + 64;                        // E
    float* dinv = (float*)(csr + E);                // Npad
    u16* bufA   = (u16*)(dinv + Npad);              // N*128 bf16 (Cs)
    u16* bufB   = bufA + (long)N * 128;             // N*128 bf16 (h)
    u16* w0hi   = bufB + (long)N * 128;
    u16* w0lo   = w0hi + 16384;
    u16* w1hi   = w0lo + 16384;
    u16* w1lo   = w1hi + 16384;
    u16* w2hi   = w1lo + 16384;
    u16* w2lo   = w2hi + 8192;

    dim3 blk(256);
    int gN = (N + 255) / 256, gE = (E + 255) / 256;
    int nb1024 = (N + 1023) / 1024;

    // ---- CSR build + norm ----
    zero_int_k<<<gN, blk, 0, stream>>>(counts, N);
    count_k<<<gE, blk, 0, stream>>>(edst, counts, E);
    dinv_k<<<gN, blk, 0, stream>>>(counts, dinv, N);
    scan1_k<<<nb1024, 1024, 0, stream>>>(counts, offs, bsum, N);
    scan2_k<<<1, 64, 0, stream>>>(bsum, nb1024);
    scan3_k<<<gN, blk, 0, stream>>>(offs, bsum, N);
    copy_int_k<<<gN, blk, 0, stream>>>(offs, cursor, N);
    fill_csr_k<<<gE, blk, 0, stream>>>(esrc, edst, cursor, csr, E);

    // ---- W prepack ----
    pack_w_k<128><<<(128 * 128 + 255) / 256, blk, 0, stream>>>(W0, 128, w0hi, w0lo);
    pack_w_k<128><<<(128 * 128 + 255) / 256, blk, 0, stream>>>(W1, 128, w1hi, w1lo);
    pack_w_k<64><<<(128 * 64 + 255) / 256, blk, 0, stream>>>(W2, 40, w2hi, w2lo);

    int gG = (N + 63) / 64;
    // ---- layer 1 ----
    mfma_gemm_f32a_k<128><<<gG, blk, 0, stream>>>(x, w0hi, w0lo, dinv, bufA, N);
    agg_ln_relu_k<<<(N + 3) / 4, blk, 0, stream>>>(bufA, offs, csr, dinv, b0, ln1g, ln1b, bufB, N);
    // ---- layer 2 ----
    mfma_gemm_bf16a_k<128><<<gG, blk, 0, stream>>>(bufB, w1hi, w1lo, dinv, bufA, N);
    agg_ln_relu_k<<<(N + 3) / 4, blk, 0, stream>>>(bufA, offs, csr, dinv, b1, ln2g, ln2b, bufB, N);
    // ---- layer 3 ----
    mfma_gemm_bf16a_k<64><<<gG, blk, 0, stream>>>(bufB, w2hi, w2lo, dinv, bufA, N);
    agg_lsm_k<<<(N + 3) / 4, blk, 0, stream>>>(bufA, offs, csr, dinv, b2, out, N);
}

// Round 5
// 213.857 us; speedup vs baseline: 16.4026x; 1.2402x over previous
//
#include <hip/hip_runtime.h>
#include <math.h>

typedef __attribute__((ext_vector_type(8))) short bf16x8;
typedef __attribute__((ext_vector_type(4))) float f32x4;
typedef unsigned short u16;

static __device__ __forceinline__ u16 f2bf(float f) {
    unsigned u = __float_as_uint(f);
    unsigned r = (u + 0x7fff + ((u >> 16) & 1)) >> 16;  // RNE
    return (u16)r;
}
static __device__ __forceinline__ float bf2f(u16 h) {
    return __uint_as_float(((unsigned)h) << 16);
}
static __device__ __forceinline__ float pk_lo(unsigned u) { return __uint_as_float(u << 16); }
static __device__ __forceinline__ float pk_hi(unsigned u) { return __uint_as_float(u & 0xffff0000u); }

// ---------------- CSR build ----------------
__global__ void zero_int_k(int* __restrict__ p, int n) {
    int i = blockIdx.x * 256 + threadIdx.x;
    if (i < n) p[i] = 0;
}
// counts[dst]++ and remember each edge's rank within its dst bucket (coalesced store)
__global__ void count_rank_k(const int* __restrict__ dst, int* __restrict__ counts,
                             int* __restrict__ rank, int e) {
    int i = blockIdx.x * 256 + threadIdx.x;
    if (i < e) rank[i] = atomicAdd(&counts[dst[i]], 1);
}
// inclusive block-local scan of counts -> offs[i+1]; block totals -> bsum; fused dinv
__global__ __launch_bounds__(1024) void scan1_k(const int* __restrict__ counts,
                                                int* __restrict__ offs,
                                                int* __restrict__ bsum,
                                                float* __restrict__ dinv, int n) {
    __shared__ int ws[16];
    int tid = threadIdx.x;
    int i = blockIdx.x * 1024 + tid;
    int lane = tid & 63, w = tid >> 6;
    int c = (i < n) ? counts[i] : 0;
    if (i < n) dinv[i] = rsqrtf((float)c + 1.0f);
    int s = c;
#pragma unroll
    for (int o = 1; o < 64; o <<= 1) { int t = __shfl_up(s, o); if (lane >= o) s += t; }
    if (lane == 63) ws[w] = s;
    __syncthreads();
    if (w == 0) {
        int x = (lane < 16) ? ws[lane] : 0;
#pragma unroll
        for (int o = 1; o < 16; o <<= 1) { int t = __shfl_up(x, o); if (lane >= o) x += t; }
        if (lane < 16) ws[lane] = x;
    }
    __syncthreads();
    int base = (w > 0) ? ws[w - 1] : 0;
    int incl = base + s;
    if (i < n) offs[i + 1] = incl;
    if (tid == 1023) bsum[blockIdx.x] = incl;
}
__global__ void scan2_k(int* __restrict__ bsum, int nb) {
    int lane = threadIdx.x;
    int v = (lane < nb) ? bsum[lane] : 0;
#pragma unroll
    for (int o = 1; o < 64; o <<= 1) { int t = __shfl_up(v, o); if (lane >= o) v += t; }
    if (lane < nb) bsum[lane] = v;
}
__global__ void scan3_k(int* __restrict__ offs, const int* __restrict__ bsum, int n) {
    int i = blockIdx.x * 256 + threadIdx.x;
    if (i == 0) offs[0] = 0;
    if (i < n) {
        int b = i >> 10;
        offs[i + 1] += (b > 0) ? bsum[b - 1] : 0;
    }
}
// atomic-free CSR fill: position known = offs[dst] + rank
__global__ void fill2_k(const int* __restrict__ src, const int* __restrict__ dst,
                        const int* __restrict__ rank, const int* __restrict__ offs,
                        int* __restrict__ csr, int e) {
    int i = blockIdx.x * 256 + threadIdx.x;
    if (i < e) csr[offs[dst[i]] + rank[i]] = src[i];
}

// ---------------- W prepack (all 3 layers in one dispatch) ----------------
// frag layout for mfma_f32_16x16x32_bf16 B-operand
__global__ void pack_all_k(const float* __restrict__ W0, const float* __restrict__ W1,
                           const float* __restrict__ W2,
                           u16* __restrict__ w0hi, u16* __restrict__ w0lo,
                           u16* __restrict__ w1hi, u16* __restrict__ w1lo,
                           u16* __restrict__ w2hi, u16* __restrict__ w2lo) {
    int i = blockIdx.x * 256 + threadIdx.x;
    const float* W; u16 *hi, *lo; int COLS, cin, idx;
    if (i < 16384)      { W = W0; hi = w0hi; lo = w0lo; COLS = 128; cin = 128; idx = i; }
    else if (i < 32768) { W = W1; hi = w1hi; lo = w1lo; COLS = 128; cin = 128; idx = i - 16384; }
    else if (i < 40960) { W = W2; hi = w2hi; lo = w2lo; COLS = 64;  cin = 40;  idx = i - 32768; }
    else return;
    int k = idx / COLS, col = idx % COLS;
    float v = (col < cin) ? W[k * cin + col] : 0.f;
    u16 h = f2bf(v);
    u16 l = f2bf(v - bf2f(h));
    int ct = col >> 4, ks = k >> 5, ln = (col & 15) + (((k >> 3) & 3) << 4), j = k & 7;
    int pos = (((ct * 4 + ks) * 64 + ln) << 3) + j;
    hi[pos] = h; lo[pos] = l;
}

// ---------------- layer-1 GEMM: fp32 A, hi/lo split (3 MFMA), bf16 C ----------------
template<int COLS>
__global__ __launch_bounds__(256) void mfma_gemm_f32a_k(const float* __restrict__ A,
                                                        const u16* __restrict__ Whi,
                                                        const u16* __restrict__ Wlo,
                                                        const float* __restrict__ dinv,
                                                        u16* __restrict__ C, int nrows) {
    int wave = threadIdx.x >> 6, lane = threadIdx.x & 63;
    int r0 = blockIdx.x * 64 + wave * 16;
    int arow = min(r0 + (lane & 15), nrows - 1);
    int kbase = (lane >> 4) * 8;

    bf16x8 ahi[4], alo[4];
#pragma unroll
    for (int ks = 0; ks < 4; ++ks) {
        const float* ap = &A[(long)arow * 128 + ks * 32 + kbase];
        float4 f0 = *(const float4*)ap;
        float4 f1 = *(const float4*)(ap + 4);
        float fv[8] = {f0.x, f0.y, f0.z, f0.w, f1.x, f1.y, f1.z, f1.w};
#pragma unroll
        for (int j = 0; j < 8; ++j) {
            u16 h = f2bf(fv[j]);
            ahi[ks][j] = (short)h;
            alo[ks][j] = (short)f2bf(fv[j] - bf2f(h));
        }
    }
    float dscale[4];
#pragma unroll
    for (int r = 0; r < 4; ++r) {
        int orow = r0 + (lane >> 4) * 4 + r;
        dscale[r] = (orow < nrows) ? dinv[orow] : 0.f;
    }
#pragma unroll
    for (int ct = 0; ct < COLS / 16; ct += 2) {
        f32x4 acc0 = {0.f, 0.f, 0.f, 0.f}, acc1 = {0.f, 0.f, 0.f, 0.f};
#pragma unroll
        for (int ks = 0; ks < 4; ++ks) {
            int fo0 = ((ct * 4 + ks) * 64 + lane) * 8;
            int fo1 = (((ct + 1) * 4 + ks) * 64 + lane) * 8;
            bf16x8 bhi0 = *(const bf16x8*)&Whi[fo0];
            bf16x8 blo0 = *(const bf16x8*)&Wlo[fo0];
            bf16x8 bhi1 = *(const bf16x8*)&Whi[fo1];
            bf16x8 blo1 = *(const bf16x8*)&Wlo[fo1];
            acc0 = __builtin_amdgcn_mfma_f32_16x16x32_bf16(ahi[ks], bhi0, acc0, 0, 0, 0);
            acc1 = __builtin_amdgcn_mfma_f32_16x16x32_bf16(ahi[ks], bhi1, acc1, 0, 0, 0);
            acc0 = __builtin_amdgcn_mfma_f32_16x16x32_bf16(alo[ks], bhi0, acc0, 0, 0, 0);
            acc1 = __builtin_amdgcn_mfma_f32_16x16x32_bf16(alo[ks], bhi1, acc1, 0, 0, 0);
            acc0 = __builtin_amdgcn_mfma_f32_16x16x32_bf16(ahi[ks], blo0, acc0, 0, 0, 0);
            acc1 = __builtin_amdgcn_mfma_f32_16x16x32_bf16(ahi[ks], blo1, acc1, 0, 0, 0);
        }
#pragma unroll
        for (int r = 0; r < 4; ++r) {
            int orow = r0 + (lane >> 4) * 4 + r;
            if (orow < nrows) {
                C[(long)orow * COLS + ct * 16 + (lane & 15)] = f2bf(acc0[r] * dscale[r]);
                C[(long)orow * COLS + (ct + 1) * 16 + (lane & 15)] = f2bf(acc1[r] * dscale[r]);
            }
        }
    }
}

// ---------------- layers 2/3 GEMM: bf16 A (2 MFMA), bf16 C ----------------
template<int COLS>
__global__ __launch_bounds__(256) void mfma_gemm_bf16a_k(const u16* __restrict__ A,
                                                         const u16* __restrict__ Whi,
                                                         const u16* __restrict__ Wlo,
                                                         const float* __restrict__ dinv,
                                                         u16* __restrict__ C, int nrows) {
    int wave = threadIdx.x >> 6, lane = threadIdx.x & 63;
    int r0 = blockIdx.x * 64 + wave * 16;
    int arow = min(r0 + (lane & 15), nrows - 1);
    int kbase = (lane >> 4) * 8;

    bf16x8 a[4];
#pragma unroll
    for (int ks = 0; ks < 4; ++ks)
        a[ks] = *(const bf16x8*)&A[(long)arow * 128 + ks * 32 + kbase];

    float dscale[4];
#pragma unroll
    for (int r = 0; r < 4; ++r) {
        int orow = r0 + (lane >> 4) * 4 + r;
        dscale[r] = (orow < nrows) ? dinv[orow] : 0.f;
    }
#pragma unroll
    for (int ct = 0; ct < COLS / 16; ct += 2) {
        f32x4 acc0 = {0.f, 0.f, 0.f, 0.f}, acc1 = {0.f, 0.f, 0.f, 0.f};
#pragma unroll
        for (int ks = 0; ks < 4; ++ks) {
            int fo0 = ((ct * 4 + ks) * 64 + lane) * 8;
            int fo1 = (((ct + 1) * 4 + ks) * 64 + lane) * 8;
            bf16x8 bhi0 = *(const bf16x8*)&Whi[fo0];
            bf16x8 blo0 = *(const bf16x8*)&Wlo[fo0];
            bf16x8 bhi1 = *(const bf16x8*)&Whi[fo1];
            bf16x8 blo1 = *(const bf16x8*)&Wlo[fo1];
            acc0 = __builtin_amdgcn_mfma_f32_16x16x32_bf16(a[ks], bhi0, acc0, 0, 0, 0);
            acc1 = __builtin_amdgcn_mfma_f32_16x16x32_bf16(a[ks], bhi1, acc1, 0, 0, 0);
            acc0 = __builtin_amdgcn_mfma_f32_16x16x32_bf16(a[ks], blo0, acc0, 0, 0, 0);
            acc1 = __builtin_amdgcn_mfma_f32_16x16x32_bf16(a[ks], blo1, acc1, 0, 0, 0);
        }
#pragma unroll
        for (int r = 0; r < 4; ++r) {
            int orow = r0 + (lane >> 4) * 4 + r;
            if (orow < nrows) {
                C[(long)orow * COLS + ct * 16 + (lane & 15)] = f2bf(acc0[r] * dscale[r]);
                C[(long)orow * COLS + (ct + 1) * 16 + (lane & 15)] = f2bf(acc1[r] * dscale[r]);
            }
        }
    }
}

// ---------------- fused CSR-gather aggregate + bias + LayerNorm + ReLU (bf16 Cs/h) ----------------
__global__ __launch_bounds__(256) void agg_ln_relu_k(const u16* __restrict__ Cs,
                                                     const int* __restrict__ offs,
                                                     const int* __restrict__ csr,
                                                     const float* __restrict__ dinv,
                                                     const float* __restrict__ bias,
                                                     const float* __restrict__ g,
                                                     const float* __restrict__ b,
                                                     u16* __restrict__ out, int n) {
    int wid = (blockIdx.x * 256 + threadIdx.x) >> 6;
    int lane = threadIdx.x & 63;
    if (wid >= n) return;
    const unsigned* C2 = (const unsigned*)Cs;
    unsigned su = C2[(long)wid * 64 + lane];
    float ax = pk_lo(su), ay = pk_hi(su), bx2 = 0.f, by2 = 0.f;
    int beg = offs[wid], end = offs[wid + 1];
    int j = beg;
    while (j < end) {
        int take = min(64, end - j);
        int myidx = (lane < take) ? csr[j + lane] : 0;
        int k = 0;
        for (; k + 8 <= take; k += 8) {
            int i0 = __shfl(myidx, k),     i1 = __shfl(myidx, k + 1);
            int i2 = __shfl(myidx, k + 2), i3 = __shfl(myidx, k + 3);
            int i4 = __shfl(myidx, k + 4), i5 = __shfl(myidx, k + 5);
            int i6 = __shfl(myidx, k + 6), i7 = __shfl(myidx, k + 7);
            unsigned u0 = C2[(long)i0 * 64 + lane], u1 = C2[(long)i1 * 64 + lane];
            unsigned u2 = C2[(long)i2 * 64 + lane], u3 = C2[(long)i3 * 64 + lane];
            unsigned u4 = C2[(long)i4 * 64 + lane], u5 = C2[(long)i5 * 64 + lane];
            unsigned u6 = C2[(long)i6 * 64 + lane], u7 = C2[(long)i7 * 64 + lane];
            ax += pk_lo(u0) + pk_lo(u1) + pk_lo(u2) + pk_lo(u3);
            ay += pk_hi(u0) + pk_hi(u1) + pk_hi(u2) + pk_hi(u3);
            bx2 += pk_lo(u4) + pk_lo(u5) + pk_lo(u6) + pk_lo(u7);
            by2 += pk_hi(u4) + pk_hi(u5) + pk_hi(u6) + pk_hi(u7);
        }
        for (; k < take; ++k) {
            int i0 = __shfl(myidx, k);
            unsigned u0 = C2[(long)i0 * 64 + lane];
            ax += pk_lo(u0); ay += pk_hi(u0);
        }
        j += take;
    }
    float w = dinv[wid];
    float2 bia = ((const float2*)bias)[lane];
    float t0 = (ax + bx2) * w + bia.x;
    float t1 = (ay + by2) * w + bia.y;
    float s = t0 + t1;
#pragma unroll
    for (int off = 32; off; off >>= 1) s += __shfl_xor(s, off);
    float mu = s * (1.f / 128.f);
    float d0 = t0 - mu, d1 = t1 - mu;
    float v = d0 * d0 + d1 * d1;
#pragma unroll
    for (int off = 32; off; off >>= 1) v += __shfl_xor(v, off);
    float rstd = rsqrtf(v * (1.f / 128.f) + 1e-5f);
    float2 gv = ((const float2*)g)[lane];
    float2 bv = ((const float2*)b)[lane];
    float y0 = fmaxf(0.f, d0 * rstd * gv.x + bv.x);
    float y1 = fmaxf(0.f, d1 * rstd * gv.y + bv.y);
    ((unsigned*)out)[(long)wid * 64 + lane] = ((unsigned)f2bf(y1) << 16) | f2bf(y0);
}

// ---------------- fused CSR-gather aggregate + bias + log_softmax (bf16 Cs, 64-col) ----------------
__global__ __launch_bounds__(256) void agg_lsm_k(const u16* __restrict__ Cs,
                                                 const int* __restrict__ offs,
                                                 const int* __restrict__ csr,
                                                 const float* __restrict__ dinv,
                                                 const float* __restrict__ b2,
                                                 float* __restrict__ out, int n) {
    int wid = (blockIdx.x * 256 + threadIdx.x) >> 6;
    int lane = threadIdx.x & 63;
    if (wid >= n) return;
    float aa = bf2f(Cs[(long)wid * 64 + lane]), ab = 0.f;
    int beg = offs[wid], end = offs[wid + 1];
    int j = beg;
    while (j < end) {
        int take = min(64, end - j);
        int myidx = (lane < take) ? csr[j + lane] : 0;
        int k = 0;
        for (; k + 8 <= take; k += 8) {
            int i0 = __shfl(myidx, k),     i1 = __shfl(myidx, k + 1);
            int i2 = __shfl(myidx, k + 2), i3 = __shfl(myidx, k + 3);
            int i4 = __shfl(myidx, k + 4), i5 = __shfl(myidx, k + 5);
            int i6 = __shfl(myidx, k + 6), i7 = __shfl(myidx, k + 7);
            float v0 = bf2f(Cs[(long)i0 * 64 + lane]), v1 = bf2f(Cs[(long)i1 * 64 + lane]);
            float v2 = bf2f(Cs[(long)i2 * 64 + lane]), v3 = bf2f(Cs[(long)i3 * 64 + lane]);
            float v4 = bf2f(Cs[(long)i4 * 64 + lane]), v5 = bf2f(Cs[(long)i5 * 64 + lane]);
            float v6 = bf2f(Cs[(long)i6 * 64 + lane]), v7 = bf2f(Cs[(long)i7 * 64 + lane]);
            aa += v0 + v1 + v2 + v3;
            ab += v4 + v5 + v6 + v7;
        }
        for (; k < take; ++k) {
            int i0 = __shfl(myidx, k);
            aa += bf2f(Cs[(long)i0 * 64 + lane]);
        }
        j += take;
    }
    float v = (lane < 40) ? (aa + ab) * dinv[wid] + b2[lane] : -INFINITY;
    float m = v;
#pragma unroll
    for (int off = 32; off; off >>= 1) m = fmaxf(m, __shfl_xor(m, off));
    float e = (lane < 40) ? expf(v - m) : 0.f;
    float s = e;
#pragma unroll
    for (int off = 32; off; off >>= 1) s += __shfl_xor(s, off);
    float r = v - m - logf(s);
    if (lane < 40) out[(long)wid * 40 + lane] = r;
}

extern "C" void kernel_launch(void* const* d_in, const int* in_sizes, int n_in,
                              void* d_out, int out_size, void* d_ws, size_t ws_size,
                              hipStream_t stream) {
    const float* x    = (const float*)d_in[0];
    const float* W0   = (const float*)d_in[1];
    const float* b0   = (const float*)d_in[2];
    const float* W1   = (const float*)d_in[3];
    const float* b1   = (const float*)d_in[4];
    const float* W2   = (const float*)d_in[5];
    const float* b2   = (const float*)d_in[6];
    const float* ln1g = (const float*)d_in[7];
    const float* ln1b = (const float*)d_in[8];
    const float* ln2g = (const float*)d_in[9];
    const float* ln2b = (const float*)d_in[10];
    const int*   ei   = (const int*)d_in[11];

    const int N = in_sizes[0] / 128;   // 50000
    const int E = in_sizes[11] / 2;    // 800000
    const int* esrc = ei;
    const int* edst = ei + E;
    float* out = (float*)d_out;

    const int Npad = ((N + 255) / 256) * 256;

    int* counts = (int*)d_ws;                       // Npad
    int* offs   = counts + Npad;                    // Npad (N+1 used)
    int* rank   = offs + Npad;                      // E
    int* bsum   = rank + E;                         // 64
    int* csr    = bsum + 64;                        // E
    float* dinv = (float*)(csr + E);                // Npad
    u16* bufA   = (u16*)(dinv + Npad);              // N*128 bf16 (Cs)
    u16* bufB   = bufA + (long)N * 128;             // N*128 bf16 (h)
    u16* w0hi   = bufB + (long)N * 128;
    u16* w0lo   = w0hi + 16384;
    u16* w1hi   = w0lo + 16384;
    u16* w1lo   = w1hi + 16384;
    u16* w2hi   = w1lo + 16384;
    u16* w2lo   = w2hi + 8192;

    dim3 blk(256);
    int gN = (N + 255) / 256, gE = (E + 255) / 256;
    int nb1024 = (N + 1023) / 1024;

    // ---- CSR build + norm ----
    zero_int_k<<<gN, blk, 0, stream>>>(counts, N);
    count_rank_k<<<gE, blk, 0, stream>>>(edst, counts, rank, E);
    scan1_k<<<nb1024, 1024, 0, stream>>>(counts, offs, bsum, dinv, N);
    scan2_k<<<1, 64, 0, stream>>>(bsum, nb1024);
    scan3_k<<<gN, blk, 0, stream>>>(offs, bsum, N);
    fill2_k<<<gE, blk, 0, stream>>>(esrc, edst, rank, offs, csr, E);

    // ---- W prepack (one dispatch) ----
    pack_all_k<<<160, blk, 0, stream>>>(W0, W1, W2, w0hi, w0lo, w1hi, w1lo, w2hi, w2lo);

    int gG = (N + 63) / 64;
    // ---- layer 1 ----
    mfma_gemm_f32a_k<128><<<gG, blk, 0, stream>>>(x, w0hi, w0lo, dinv, bufA, N);
    agg_ln_relu_k<<<(N + 3) / 4, blk, 0, stream>>>(bufA, offs, csr, dinv, b0, ln1g, ln1b, bufB, N);
    // ---- layer 2 ----
    mfma_gemm_bf16a_k<128><<<gG, blk, 0, stream>>>(bufB, w1hi, w1lo, dinv, bufA, N);
    agg_ln_relu_k<<<(N + 3) / 4, blk, 0, stream>>>(bufA, offs, csr, dinv, b1, ln2g, ln2b, bufB, N);
    // ---- layer 3 ----
    mfma_gemm_bf16a_k<64><<<gG, blk, 0, stream>>>(bufB, w2hi, w2lo, dinv, bufA, N);
    agg_lsm_k<<<(N + 3) / 4, blk, 0, stream>>>(bufA, offs, csr, dinv, b2, out, N);
}